// Round 4
// baseline (3999.228 us; speedup 1.0000x reference)
//
#include <hip/hip_runtime.h>
#include <math.h>

// Dims (fixed)
#define B_ 256
#define L_ 128
#define C_ 256
#define H_ 512
#define N4H 2048
#define TCH 8            // steps per chunk
#define NCH 16           // chunks

// Algebra (verified R2/R3):
//   gates_t = G2_t + h_{t-1} @ W2 ;  W2 = Wmh@Whm ; Weff = Wih + Wmx@Whm
//   beff = bih + bhm + (bmx+bmh)@Whm ; G2 = x@Weff + beff
//   alpha_t is t-invariant -> x_tilde fully parallel.
// R4: ONE persistent kernel runs all 128 steps. 256 blocks (rg 0..7 x ng 0..31),
// block = 32 batch rows x 64 gate-cols. W2 frags live in VGPRs for the whole
// kernel; c-state in registers; h exchanged via global double-buffer with a
// per-rowgroup (32-block) sense barrier. G2 chunks computed in-kernel (block-
// private, no sync). Split-bf16 (hi/lo, drop lo*lo) everywhere.

typedef float f32x4 __attribute__((ext_vector_type(4)));
typedef short short8 __attribute__((ext_vector_type(8)));

__device__ __forceinline__ float sigm(float x){ return 1.f/(1.f+expf(-x)); }

__device__ __forceinline__ void splitbf(float v, short& hi, short& lo) {
  union { float f; unsigned u; } a; a.f = v;
  unsigned r = (a.u + 0x7fffu + ((a.u >> 16) & 1u)) >> 16;
  hi = (short)r;
  union { unsigned u; float f; } h; h.u = r << 16;
  float res = v - h.f;
  union { float f; unsigned u; } b; b.f = res;
  unsigned r2 = (b.u + 0x7fffu + ((b.u >> 16) & 1u)) >> 16;
  lo = (short)r2;
}

// ---------------------------------------------------------------------------
// x_tilde (verified R2/R3)
// ---------------------------------------------------------------------------
__global__ __launch_bounds__(256) void xtilde_kernel(
    const float* __restrict__ x, const float* __restrict__ Wa,
    const float* __restrict__ ba, float* __restrict__ xt_out)
{
  const int b = blockIdx.x;
  const int c = threadIdx.x;
  const float* Wax = Wa + 2*H_;
  const float* xb  = x + (size_t)b*L_*C_;
  float s = 0.f;
  #pragma unroll 4
  for (int l = 0; l < L_; ++l) s += xb[(size_t)l*C_ + c] * Wax[l];
  s += ba[0];
  __shared__ float red[256];
  red[c] = s; __syncthreads();
  for (int off = 128; off > 0; off >>= 1) {
    if (c < off) red[c] = fmaxf(red[c], red[c+off]);
    __syncthreads();
  }
  const float m = red[0]; __syncthreads();
  const float e = expf(s - m);
  red[c] = e; __syncthreads();
  for (int off = 128; off > 0; off >>= 1) {
    if (c < off) red[c] += red[c+off];
    __syncthreads();
  }
  const float alpha = e / red[0];
  float* ob = xt_out + (size_t)b*L_*C_;
  #pragma unroll 4
  for (int l = 0; l < L_; ++l) ob[(size_t)l*C_ + c] = alpha * xb[(size_t)l*C_ + c];
}

// ---------------------------------------------------------------------------
// beff_p[n'] permuted: n' = (n&511)*4 + (n>>9)   (verified R3)
// ---------------------------------------------------------------------------
__global__ __launch_bounds__(256) void beff_kernel(
    const float* __restrict__ bih, const float* __restrict__ bhm,
    const float* __restrict__ bmx, const float* __restrict__ bmh,
    const float* __restrict__ Whm, float* __restrict__ beff)
{
  int n = blockIdx.x*256 + threadIdx.x;
  float s = bih[n] + bhm[n];
  for (int k = 0; k < H_; ++k) s += (bmx[k]+bmh[k]) * Whm[(long)k*N4H + n];
  beff[(n & 511)*4 + (n >> 9)] = s;
}

// ---------------------------------------------------------------------------
// Fold GEMM (R3 body, verified): Out[r][c] = sum_k A[r,k]*Whm[k,c] (+addmat).
// Epilogue: split-bf16 + scatter into MFMA B-frag swizzled layout:
//   n' = (c&511)*4 + (c>>9); ng=n'>>6; nt=(n'>>4)&3; lcc=n'&15;
//   kf=r>>5; lkk=(r>>3)&3; jj=r&7;
//   idx = (((ng*4+nt)*kfrags + kf)*64 + lkk*16 + lcc)*8 + jj
// ---------------------------------------------------------------------------
__global__ __launch_bounds__(256) void gemm_fold(
    const float* __restrict__ A, int lda,
    const float* __restrict__ Bm,
    const float* __restrict__ addmat,
    short* __restrict__ ohi, short* __restrict__ olo, int kfrags)
{
  constexpr int BM=64, BN=64, BK=16, PAD=4;
  __shared__ float Xs[BK][BM+PAD];
  __shared__ float Ws[BK][BN+PAD];
  const int tid = threadIdx.x;
  const int row0 = blockIdx.y*BM, col0 = blockIdx.x*BN;
  const int tx = tid & 15, ty = tid >> 4;
  float acc[4][4] = {};

  for (int k0 = 0; k0 < H_; k0 += BK) {
    {
      int m = tid >> 2, q = tid & 3;
      const float4 v = *(const float4*)&A[(long)(row0+m)*lda + k0 + q*4];
      Xs[q*4+0][m] = v.x; Xs[q*4+1][m] = v.y; Xs[q*4+2][m] = v.z; Xs[q*4+3][m] = v.w;
    }
    {
      int kk = tid >> 4, c4 = tid & 15;
      *(float4*)&Ws[kk][c4*4] = *(const float4*)&Bm[(long)(k0+kk)*N4H + col0 + c4*4];
    }
    __syncthreads();
    #pragma unroll
    for (int kk = 0; kk < BK; ++kk) {
      float4 xv = *(const float4*)&Xs[kk][ty*4];
      float4 wv = *(const float4*)&Ws[kk][tx*4];
      const float xs[4] = {xv.x,xv.y,xv.z,xv.w};
      const float ws[4] = {wv.x,wv.y,wv.z,wv.w};
      #pragma unroll
      for (int i=0;i<4;++i)
        #pragma unroll
        for (int j=0;j<4;++j) acc[i][j] += xs[i]*ws[j];
    }
    __syncthreads();
  }
  #pragma unroll
  for (int i=0;i<4;++i) {
    int r = row0 + ty*4 + i;
    int kf = r >> 5, lkk = (r >> 3) & 3, jj = r & 7;
    #pragma unroll
    for (int j=0;j<4;++j) {
      int c = col0 + tx*4 + j;
      float v = acc[i][j];
      if (addmat) v += addmat[(long)r*N4H + c];
      int np = (c & 511)*4 + (c >> 9);
      int ng = np >> 6, nt = (np >> 4) & 3, lcc = np & 15;
      long idx = ((((long)ng*4 + nt)*kfrags + kf)*64 + lkk*16 + lcc)*8 + jj;
      short hi, lo; splitbf(v, hi, lo);
      ohi[idx] = hi; olo[idx] = lo;
    }
  }
}

__global__ void init_bar(int* bar){ bar[threadIdx.x] = 0; }

// ---------------------------------------------------------------------------
// Persistent recurrence kernel. 256 blocks x 512 threads, 64 KB LDS,
// 1 block/CU -> all co-resident (plain launch).
// ---------------------------------------------------------------------------
__global__ __launch_bounds__(512, 2) void persist_kernel(
    const float* __restrict__ x,
    const short* __restrict__ Wfh, const short* __restrict__ Wfl, // swizzled kf=8
    const short* __restrict__ W2h, const short* __restrict__ W2l, // swizzled kf=16
    const float* __restrict__ beff_p,
    float* __restrict__ G2ws,           // [256 blk][256 cr][64 nl]
    short* __restrict__ hb_h, short* __restrict__ hb_l, // [2][256][512]
    float* __restrict__ hseq, float* __restrict__ cseq,
    int* __restrict__ bar)              // cnt[0..127], gen[128..255]
{
  __shared__ short lds[32768];          // 64 KB: hi at [0..16383], lo at +16384
  const int tid = threadIdx.x;
  const int lane = tid & 63, w = tid >> 6;
  const int lc = lane & 15, lk = lane >> 4;
  const int blk = blockIdx.x;
  const int rg = blk & 7, ng = blk >> 3;
  const int nt = w & 3, rh = w >> 2;    // wave: ntile 0..3, row-half 0..1
  int* cnt = bar + rg*16;
  int* gen = bar + 128 + rg*16;

  // persistent W2 frags in registers (128 VGPRs)
  short8 w2h[16], w2l[16];
  #pragma unroll
  for (int kf = 0; kf < 16; ++kf) {
    const long o = ((((long)ng*4 + nt)*16 + kf)*64 + lane)*8;
    w2h[kf] = *(const short8*)(W2h + o);
    w2l[kf] = *(const short8*)(W2l + o);
  }
  const float beffv = beff_p[ng*64 + nt*16 + lc];
  float* G2b = G2ws + (long)blk*16384;
  f32x4 cstate = {0.f,0.f,0.f,0.f};
  const bool leader = ((lane & 3) == 0);
  const int jglob = ng*16 + nt*4 + (lc >> 2);

  for (int ch = 0; ch < NCH; ++ch) {
    const int t0 = ch*TCH;
    // ---- G2 chunk: 4 sub-phases of 64 chunk-rows (cr = b_local*8 + tl) ----
    for (int sp = 0; sp < 4; ++sp) {
      __syncthreads();
      { // stage x sub-phase, split to bf16 hi/lo in MFMA A-frag layout
        const int r = tid & 63, kq = tid >> 6;      // kq 0..7 (32 k each)
        const int cr = sp*64 + r;
        const int bl = cr >> 3, tl = cr & 7;
        const float* xp = x + ((long)(rg*32 + bl)*L_ + t0 + tl)*C_ + kq*32;
        const int rt = r >> 4, m = r & 15;
        #pragma unroll
        for (int s = 0; s < 4; ++s) {
          float4 v0 = *(const float4*)(xp + s*8);
          float4 v1 = *(const float4*)(xp + s*8 + 4);
          short8 hi, lo;
          { short a,b; splitbf(v0.x,a,b); hi[0]=a; lo[0]=b; }
          { short a,b; splitbf(v0.y,a,b); hi[1]=a; lo[1]=b; }
          { short a,b; splitbf(v0.z,a,b); hi[2]=a; lo[2]=b; }
          { short a,b; splitbf(v0.w,a,b); hi[3]=a; lo[3]=b; }
          { short a,b; splitbf(v1.x,a,b); hi[4]=a; lo[4]=b; }
          { short a,b; splitbf(v1.y,a,b); hi[5]=a; lo[5]=b; }
          { short a,b; splitbf(v1.z,a,b); hi[6]=a; lo[6]=b; }
          { short a,b; splitbf(v1.w,a,b); hi[7]=a; lo[7]=b; }
          const int idx = (((rt*8 + kq)*64) + s*16 + m)*8;
          *(short8*)(lds + idx) = hi;
          *(short8*)(lds + 16384 + idx) = lo;
        }
      }
      __syncthreads();
      #pragma unroll
      for (int rt2 = 0; rt2 < 2; ++rt2) {
        const int rt = rh*2 + rt2;
        f32x4 acc = {0.f,0.f,0.f,0.f};
        #pragma unroll
        for (int kf = 0; kf < 8; ++kf) {
          const int ia = ((rt*8 + kf)*64 + lane)*8;
          short8 a  = *(const short8*)(lds + ia);
          short8 al = *(const short8*)(lds + 16384 + ia);
          const long ow = ((((long)ng*4 + nt)*8 + kf)*64 + lane)*8;
          short8 bh = *(const short8*)(Wfh + ow);
          short8 bl = *(const short8*)(Wfl + ow);
          acc = __builtin_amdgcn_mfma_f32_16x16x32_bf16(al, bh, acc, 0,0,0);
          acc = __builtin_amdgcn_mfma_f32_16x16x32_bf16(a,  bl, acc, 0,0,0);
          acc = __builtin_amdgcn_mfma_f32_16x16x32_bf16(a,  bh, acc, 0,0,0);
        }
        #pragma unroll
        for (int r4 = 0; r4 < 4; ++r4) {
          const int cr = sp*64 + rt*16 + lk*4 + r4;
          G2b[cr*64 + nt*16 + lc] = acc[r4];
        }
      }
    }
    // ---- 8 steps ----
    for (int tl = 0; tl < TCH; ++tl) {
      const int t = t0 + tl;
      __syncthreads();
      if (t > 0) { // stage h_{t-1} (already split) into LDS A-frag layout
        const int rl = tid & 31, kq = tid >> 5;     // kq 0..15
        const long src = ((long)((t-1)&1)*B_ + rg*32 + rl)*H_ + kq*32;
        const int rt = rl >> 4, m = rl & 15;
        #pragma unroll
        for (int s = 0; s < 4; ++s) {
          short8 hv = *(const short8*)(hb_h + src + s*8);
          short8 lv = *(const short8*)(hb_l + src + s*8);
          const int idx = (((rt*16 + kq)*64) + s*16 + m)*8;
          *(short8*)(lds + idx) = hv;
          *(short8*)(lds + 16384 + idx) = lv;
        }
      }
      __syncthreads();
      f32x4 acca = {0.f,0.f,0.f,0.f}, accb = {0.f,0.f,0.f,0.f};
      if (t > 0) {
        #pragma unroll
        for (int kf = 0; kf < 16; kf += 2) {
          const int ia = ((rh*16 + kf)*64 + lane)*8;
          short8 a0  = *(const short8*)(lds + ia);
          short8 a0l = *(const short8*)(lds + 16384 + ia);
          short8 a1  = *(const short8*)(lds + ia + 512);
          short8 a1l = *(const short8*)(lds + 16384 + ia + 512);
          acca = __builtin_amdgcn_mfma_f32_16x16x32_bf16(a0l, w2h[kf],   acca, 0,0,0);
          accb = __builtin_amdgcn_mfma_f32_16x16x32_bf16(a1l, w2h[kf+1], accb, 0,0,0);
          acca = __builtin_amdgcn_mfma_f32_16x16x32_bf16(a0,  w2l[kf],   acca, 0,0,0);
          accb = __builtin_amdgcn_mfma_f32_16x16x32_bf16(a1,  w2l[kf+1], accb, 0,0,0);
          acca = __builtin_amdgcn_mfma_f32_16x16x32_bf16(a0,  w2h[kf],   acca, 0,0,0);
          accb = __builtin_amdgcn_mfma_f32_16x16x32_bf16(a1,  w2h[kf+1], accb, 0,0,0);
        }
      }
      // epilogue: gates -> cell (c in registers), write outputs + h buffers
      #pragma unroll
      for (int r4 = 0; r4 < 4; ++r4) {
        const int blocal = rh*16 + lk*4 + r4;
        const int cr = blocal*8 + tl;
        float v = acca[r4] + accb[r4] + beffv + G2b[cr*64 + nt*16 + lc];
        const int qb = lane & ~3;
        float iv = __shfl(v, qb+0, 64);
        float fv = __shfl(v, qb+1, 64);
        float gv = __shfl(v, qb+2, 64);
        float ov = __shfl(v, qb+3, 64);
        if (leader) {
          float cnew = sigm(fv)*cstate[r4] + sigm(iv)*tanhf(gv);
          float hnew = sigm(ov)*tanhf(cnew);
          cstate[r4] = cnew;
          const int b = rg*32 + blocal;
          hseq[((long)b*L_ + t)*H_ + jglob] = hnew;
          cseq[((long)b*L_ + t)*H_ + jglob] = cnew;
          short hh, hl; splitbf(hnew, hh, hl);
          const long ho = ((long)(t&1)*B_ + b)*H_ + jglob;
          hb_h[ho] = hh; hb_l[ho] = hl;
        }
      }
      // per-rowgroup barrier (32 blocks), skip after last step
      if (t < L_-1) {
        __syncthreads();              // all waves' stores issued & drained (vmcnt before barrier)
        if (tid == 0) {
          __threadfence();            // release h writes (agent scope)
          if (atomicAdd(cnt, 1) == 31) {
            __hip_atomic_store(cnt, 0, __ATOMIC_RELAXED, __HIP_MEMORY_SCOPE_AGENT);
            __hip_atomic_store(gen, t+1, __ATOMIC_RELEASE, __HIP_MEMORY_SCOPE_AGENT);
          } else {
            while (__hip_atomic_load(gen, __ATOMIC_ACQUIRE, __HIP_MEMORY_SCOPE_AGENT) < t+1)
              __builtin_amdgcn_s_sleep(2);
          }
          __threadfence();            // acquire: invalidate stale cached h
        }
        __syncthreads();
      }
    }
  }
}

// ---------------------------------------------------------------------------
extern "C" void kernel_launch(void* const* d_in, const int* in_sizes, int n_in,
                              void* d_out, int out_size, void* d_ws, size_t ws_size,
                              hipStream_t stream)
{
  const float* x   = (const float*)d_in[0];
  const float* Wih = (const float*)d_in[1];
  const float* bih = (const float*)d_in[2];
  const float* Wmx = (const float*)d_in[3];
  const float* bmx = (const float*)d_in[4];
  const float* Wmh = (const float*)d_in[5];
  const float* bmh = (const float*)d_in[6];
  const float* Whm = (const float*)d_in[7];
  const float* bhm = (const float*)d_in[8];
  const float* Wa  = (const float*)d_in[9];
  const float* ba  = (const float*)d_in[10];

  float* out  = (float*)d_out;
  float* hseq = out;                           // (B, L, H)
  float* cseq = out + (size_t)B_*L_*H_;        // (B, L, H)
  float* xt   = out + (size_t)2*B_*L_*H_;      // (B, L, C)

  // ws carve (~23.3 MB)
  float* G2ws   = (float*)d_ws;                         // 256*16384 f = 16 MB
  float* beff_p = G2ws + (size_t)256*16384;             // 2048 f
  short* W2h = (short*)(beff_p + N4H);                  // 2048*512
  short* W2l = W2h + (size_t)N4H*H_;
  short* Wfh = W2l + (size_t)N4H*H_;                    // 2048*256
  short* Wfl = Wfh + (size_t)N4H*C_;
  short* hbh = Wfl + (size_t)N4H*C_;                    // 2*256*512
  short* hbl = hbh + (size_t)2*B_*H_;
  int*   bar = (int*)(hbl + (size_t)2*B_*H_);           // 256 ints

  xtilde_kernel<<<B_, 256, 0, stream>>>(x, Wa, ba, xt);
  beff_kernel<<<N4H/256, 256, 0, stream>>>(bih, bhm, bmx, bmh, Whm, beff_p);
  // W2 = Wmh@Whm  -> swizzled frag layout, kfrags=16 (K-dim 512)
  gemm_fold<<<dim3(N4H/64, H_/64), 256, 0, stream>>>(
      Wmh, H_, Whm, nullptr, W2h, W2l, 16);
  // Weff = Wmx@Whm + Wih -> swizzled, kfrags=8 (K-dim 256)
  gemm_fold<<<dim3(N4H/64, C_/64), 256, 0, stream>>>(
      Wmx, H_, Whm, Wih, Wfh, Wfl, 8);
  init_bar<<<1, 256, 0, stream>>>(bar);

  persist_kernel<<<256, 512, 0, stream>>>(
      x, Wfh, Wfl, W2h, W2l, beff_p, G2ws, hbh, hbl, hseq, cseq, bar);
}

// Round 5
// 1387.066 us; speedup vs baseline: 2.8832x; 2.8832x over previous
//
#include <hip/hip_runtime.h>
#include <math.h>

// Dims (fixed)
#define B_ 256
#define L_ 128
#define C_ 256
#define H_ 512
#define N4H 2048
#define TCH 8            // steps per chunk
#define NCH 16           // chunks

// Algebra (verified R2-R4):
//   gates_t = G2_t + h_{t-1} @ W2 ;  W2 = Wmh@Whm ; Weff = Wih + Wmx@Whm
//   beff = bih + bhm + (bmx+bmh)@Whm ; G2 = x@Weff + beff
//   alpha_t is t-invariant -> x_tilde fully parallel.
// R5 vs R4: NO __threadfence (it compiled to per-step L2 writeback/inv -> 340MB
// of extra HBM write traffic + ~29us/step stall). Cross-block h goes through
// agent-scope (sc1) relaxed atomics that bypass L1/L2 per-access; barrier is a
// monotonic counter. Partition: 16 rowgroups(16 rows) x 16 ngroups(128 n').
// W2 slice stays in VGPRs for the whole kernel; c-state in registers.

typedef float f32x4 __attribute__((ext_vector_type(4)));
typedef short short8 __attribute__((ext_vector_type(8)));

__device__ __forceinline__ float sigm(float x){ return 1.f/(1.f+expf(-x)); }

__device__ __forceinline__ void splitbf(float v, short& hi, short& lo) {
  union { float f; unsigned u; } a; a.f = v;
  unsigned r = (a.u + 0x7fffu + ((a.u >> 16) & 1u)) >> 16;
  hi = (short)r;
  union { unsigned u; float f; } h; h.u = r << 16;
  float res = v - h.f;
  union { float f; unsigned u; } b; b.f = res;
  unsigned r2 = (b.u + 0x7fffu + ((b.u >> 16) & 1u)) >> 16;
  lo = (short)r2;
}

// ---------------------------------------------------------------------------
// x_tilde (verified R2-R4)
// ---------------------------------------------------------------------------
__global__ __launch_bounds__(256) void xtilde_kernel(
    const float* __restrict__ x, const float* __restrict__ Wa,
    const float* __restrict__ ba, float* __restrict__ xt_out)
{
  const int b = blockIdx.x;
  const int c = threadIdx.x;
  const float* Wax = Wa + 2*H_;
  const float* xb  = x + (size_t)b*L_*C_;
  float s = 0.f;
  #pragma unroll 4
  for (int l = 0; l < L_; ++l) s += xb[(size_t)l*C_ + c] * Wax[l];
  s += ba[0];
  __shared__ float red[256];
  red[c] = s; __syncthreads();
  for (int off = 128; off > 0; off >>= 1) {
    if (c < off) red[c] = fmaxf(red[c], red[c+off]);
    __syncthreads();
  }
  const float m = red[0]; __syncthreads();
  const float e = expf(s - m);
  red[c] = e; __syncthreads();
  for (int off = 128; off > 0; off >>= 1) {
    if (c < off) red[c] += red[c+off];
    __syncthreads();
  }
  const float alpha = e / red[0];
  float* ob = xt_out + (size_t)b*L_*C_;
  #pragma unroll 4
  for (int l = 0; l < L_; ++l) ob[(size_t)l*C_ + c] = alpha * xb[(size_t)l*C_ + c];
}

// ---------------------------------------------------------------------------
// beff_p[n'] permuted: n' = (n&511)*4 + (n>>9)   (verified R3/R4)
// ---------------------------------------------------------------------------
__global__ __launch_bounds__(256) void beff_kernel(
    const float* __restrict__ bih, const float* __restrict__ bhm,
    const float* __restrict__ bmx, const float* __restrict__ bmh,
    const float* __restrict__ Whm, float* __restrict__ beff)
{
  int n = blockIdx.x*256 + threadIdx.x;
  float s = bih[n] + bhm[n];
  for (int k = 0; k < H_; ++k) s += (bmx[k]+bmh[k]) * Whm[(long)k*N4H + n];
  beff[(n & 511)*4 + (n >> 9)] = s;
}

// ---------------------------------------------------------------------------
// Fold GEMM (R3/R4 body, verified). Epilogue scatters split-bf16 into MFMA
// B-frag swizzle for the NEW partition (ng 0..15 wide-128, nt 0..7):
//   n' = (c&511)*4 + (c>>9); ng=n'>>7; nt=(n'>>4)&7; lcc=n'&15
//   kf=r>>5; lkk=(r>>3)&3; jj=r&7
//   idx = (((ng*8+nt)*kfrags + kf)*64 + lkk*16 + lcc)*8 + jj
// ---------------------------------------------------------------------------
__global__ __launch_bounds__(256) void gemm_fold(
    const float* __restrict__ A, int lda,
    const float* __restrict__ Bm,
    const float* __restrict__ addmat,
    short* __restrict__ ohi, short* __restrict__ olo, int kfrags)
{
  constexpr int BM=64, BN=64, BK=16, PAD=4;
  __shared__ float Xs[BK][BM+PAD];
  __shared__ float Ws[BK][BN+PAD];
  const int tid = threadIdx.x;
  const int row0 = blockIdx.y*BM, col0 = blockIdx.x*BN;
  const int tx = tid & 15, ty = tid >> 4;
  float acc[4][4] = {};

  for (int k0 = 0; k0 < H_; k0 += BK) {
    {
      int m = tid >> 2, q = tid & 3;
      const float4 v = *(const float4*)&A[(long)(row0+m)*lda + k0 + q*4];
      Xs[q*4+0][m] = v.x; Xs[q*4+1][m] = v.y; Xs[q*4+2][m] = v.z; Xs[q*4+3][m] = v.w;
    }
    {
      int kk = tid >> 4, c4 = tid & 15;
      *(float4*)&Ws[kk][c4*4] = *(const float4*)&Bm[(long)(k0+kk)*N4H + col0 + c4*4];
    }
    __syncthreads();
    #pragma unroll
    for (int kk = 0; kk < BK; ++kk) {
      float4 xv = *(const float4*)&Xs[kk][ty*4];
      float4 wv = *(const float4*)&Ws[kk][tx*4];
      const float xs[4] = {xv.x,xv.y,xv.z,xv.w};
      const float ws[4] = {wv.x,wv.y,wv.z,wv.w};
      #pragma unroll
      for (int i=0;i<4;++i)
        #pragma unroll
        for (int j=0;j<4;++j) acc[i][j] += xs[i]*ws[j];
    }
    __syncthreads();
  }
  #pragma unroll
  for (int i=0;i<4;++i) {
    int r = row0 + ty*4 + i;
    int kf = r >> 5, lkk = (r >> 3) & 3, jj = r & 7;
    #pragma unroll
    for (int j=0;j<4;++j) {
      int c = col0 + tx*4 + j;
      float v = acc[i][j];
      if (addmat) v += addmat[(long)r*N4H + c];
      int np = (c & 511)*4 + (c >> 9);
      int ng = np >> 7, nt = (np >> 4) & 7, lcc = np & 15;
      long idx = ((((long)ng*8 + nt)*kfrags + kf)*64 + lkk*16 + lcc)*8 + jj;
      short hi, lo; splitbf(v, hi, lo);
      ohi[idx] = hi; olo[idx] = lo;
    }
  }
}

__global__ void init_bar(int* bar){ bar[threadIdx.x] = 0; }

// ---------------------------------------------------------------------------
// Persistent recurrence kernel. 256 blocks x 512 threads, 64 KB LDS,
// 1 block/CU. Block (rg,ng) = 16 batch rows x 128 gate-cols, all 128 steps.
// ---------------------------------------------------------------------------
__global__ __launch_bounds__(512, 2) void persist_kernel(
    const float* __restrict__ x,
    const short* __restrict__ Wfh, const short* __restrict__ Wfl, // swizzled kf=8
    const short* __restrict__ W2h, const short* __restrict__ W2l, // swizzled kf=16
    const float* __restrict__ beff_p,
    float* __restrict__ G2ws,           // [256 blk][128 cr][128 nl]
    unsigned* __restrict__ hb,          // [2][256][512] packed (hi | lo<<16)
    float* __restrict__ hseq, float* __restrict__ cseq,
    int* __restrict__ bar)              // cnt per rowgroup, stride 32 ints
{
  __shared__ short lds[32768];          // 64 KB: hi [0..16383], lo [16384..]
  const int tid = threadIdx.x;
  const int lane = tid & 63, w = tid >> 6;   // w = n-tile 0..7
  const int lc = lane & 15, lk = lane >> 4;
  const int blk = blockIdx.x;
  const int rg = blk & 15, ng = blk >> 4;
  int* cnt = bar + rg*32;

  // persistent W2 frags in registers (128 VGPRs)
  short8 w2h[16], w2l[16];
  #pragma unroll
  for (int kf = 0; kf < 16; ++kf) {
    const long o = ((((long)ng*8 + w)*16 + kf)*64 + lane)*8;
    w2h[kf] = *(const short8*)(W2h + o);
    w2l[kf] = *(const short8*)(W2l + o);
  }
  const float beffv = beff_p[ng*128 + w*16 + lc];
  float* G2b = G2ws + (long)blk*16384;
  f32x4 cstate = {0.f,0.f,0.f,0.f};
  const bool leader = ((lane & 3) == 0);
  const int jglob = ng*32 + w*4 + (lc >> 2);

  for (int ch = 0; ch < NCH; ++ch) {
    const int t0 = ch*TCH;
    // ---- G2 chunk: 2 sub-phases of 64 chunk-rows (cr = b_local*8 + tl) ----
    for (int sp = 0; sp < 2; ++sp) {
      __syncthreads();
      { // stage x sub-phase, split to bf16 hi/lo in MFMA A-frag layout
        const int r = tid & 63, kq = tid >> 3 >> 3;   // kq = tid>>6, 0..7
        const int cr = sp*64 + r;
        const int bl = cr >> 3, tl = cr & 7;
        const float* xp = x + ((long)(rg*16 + bl)*L_ + t0 + tl)*C_ + kq*32;
        const int rt = r >> 4, m = r & 15;
        #pragma unroll
        for (int s = 0; s < 4; ++s) {
          float4 v0 = *(const float4*)(xp + s*8);
          float4 v1 = *(const float4*)(xp + s*8 + 4);
          short8 hi, lo;
          { short a,b; splitbf(v0.x,a,b); hi[0]=a; lo[0]=b; }
          { short a,b; splitbf(v0.y,a,b); hi[1]=a; lo[1]=b; }
          { short a,b; splitbf(v0.z,a,b); hi[2]=a; lo[2]=b; }
          { short a,b; splitbf(v0.w,a,b); hi[3]=a; lo[3]=b; }
          { short a,b; splitbf(v1.x,a,b); hi[4]=a; lo[4]=b; }
          { short a,b; splitbf(v1.y,a,b); hi[5]=a; lo[5]=b; }
          { short a,b; splitbf(v1.z,a,b); hi[6]=a; lo[6]=b; }
          { short a,b; splitbf(v1.w,a,b); hi[7]=a; lo[7]=b; }
          const int idx = (((rt*8 + kq)*64) + s*16 + m)*8;
          *(short8*)(lds + idx) = hi;
          *(short8*)(lds + 16384 + idx) = lo;
        }
      }
      __syncthreads();
      #pragma unroll
      for (int rt2 = 0; rt2 < 4; ++rt2) {
        f32x4 acc = {0.f,0.f,0.f,0.f};
        #pragma unroll
        for (int kf = 0; kf < 8; ++kf) {
          const int ia = ((rt2*8 + kf)*64 + lane)*8;
          short8 a  = *(const short8*)(lds + ia);
          short8 al = *(const short8*)(lds + 16384 + ia);
          const long ow = ((((long)ng*8 + w)*8 + kf)*64 + lane)*8;
          short8 bh = *(const short8*)(Wfh + ow);
          short8 bl = *(const short8*)(Wfl + ow);
          acc = __builtin_amdgcn_mfma_f32_16x16x32_bf16(al, bh, acc, 0,0,0);
          acc = __builtin_amdgcn_mfma_f32_16x16x32_bf16(a,  bl, acc, 0,0,0);
          acc = __builtin_amdgcn_mfma_f32_16x16x32_bf16(a,  bh, acc, 0,0,0);
        }
        #pragma unroll
        for (int r4 = 0; r4 < 4; ++r4) {
          const int cr = sp*64 + rt2*16 + lk*4 + r4;
          G2b[cr*128 + w*16 + lc] = acc[r4];
        }
      }
    }
    // ---- 8 steps ----
    for (int tl = 0; tl < TCH; ++tl) {
      const int t = t0 + tl;
      __syncthreads();
      if (t > 0) { // stage h_{t-1}: agent-scope (sc1) loads, unpack, LDS A-frag
        const int rl = tid & 15, kq = tid >> 4;     // kq 0..31, 16 k each
        const unsigned* hp =
            hb + ((long)((t-1)&1)*B_ + rg*16 + rl)*H_ + kq*16;
        #pragma unroll
        for (int g = 0; g < 2; ++g) {
          unsigned long long v0 = __hip_atomic_load(
              (const unsigned long long*)(hp + g*8) + 0,
              __ATOMIC_RELAXED, __HIP_MEMORY_SCOPE_AGENT);
          unsigned long long v1 = __hip_atomic_load(
              (const unsigned long long*)(hp + g*8) + 1,
              __ATOMIC_RELAXED, __HIP_MEMORY_SCOPE_AGENT);
          unsigned long long v2 = __hip_atomic_load(
              (const unsigned long long*)(hp + g*8) + 2,
              __ATOMIC_RELAXED, __HIP_MEMORY_SCOPE_AGENT);
          unsigned long long v3 = __hip_atomic_load(
              (const unsigned long long*)(hp + g*8) + 3,
              __ATOMIC_RELAXED, __HIP_MEMORY_SCOPE_AGENT);
          unsigned u[8] = {(unsigned)v0, (unsigned)(v0>>32),
                           (unsigned)v1, (unsigned)(v1>>32),
                           (unsigned)v2, (unsigned)(v2>>32),
                           (unsigned)v3, (unsigned)(v3>>32)};
          short8 hi, lo;
          #pragma unroll
          for (int e = 0; e < 8; ++e) {
            hi[e] = (short)(u[e] & 0xffffu);
            lo[e] = (short)(u[e] >> 16);
          }
          const int kf = kq >> 1, s = (kq & 1)*2 + g;
          const int idx = (kf*64 + s*16 + rl)*8;
          *(short8*)(lds + idx) = hi;
          *(short8*)(lds + 16384 + idx) = lo;
        }
      }
      __syncthreads();
      f32x4 acca = {0.f,0.f,0.f,0.f}, accb = {0.f,0.f,0.f,0.f};
      if (t > 0) {
        #pragma unroll
        for (int kf = 0; kf < 16; kf += 2) {
          const int ia = (kf*64 + lane)*8;
          short8 a0  = *(const short8*)(lds + ia);
          short8 a0l = *(const short8*)(lds + 16384 + ia);
          short8 a1  = *(const short8*)(lds + ia + 512);
          short8 a1l = *(const short8*)(lds + 16384 + ia + 512);
          acca = __builtin_amdgcn_mfma_f32_16x16x32_bf16(a0l, w2h[kf],   acca, 0,0,0);
          accb = __builtin_amdgcn_mfma_f32_16x16x32_bf16(a1l, w2h[kf+1], accb, 0,0,0);
          acca = __builtin_amdgcn_mfma_f32_16x16x32_bf16(a0,  w2l[kf],   acca, 0,0,0);
          accb = __builtin_amdgcn_mfma_f32_16x16x32_bf16(a1,  w2l[kf+1], accb, 0,0,0);
          acca = __builtin_amdgcn_mfma_f32_16x16x32_bf16(a0,  w2h[kf],   acca, 0,0,0);
          accb = __builtin_amdgcn_mfma_f32_16x16x32_bf16(a1,  w2h[kf+1], accb, 0,0,0);
        }
      }
      // epilogue: gates -> cell (c in registers), outputs + packed h store
      #pragma unroll
      for (int r4 = 0; r4 < 4; ++r4) {
        const int blocal = lk*4 + r4;
        const int cr = blocal*8 + tl;
        float v = acca[r4] + accb[r4] + beffv + G2b[cr*128 + w*16 + lc];
        const int qb = lane & ~3;
        float iv = __shfl(v, qb+0, 64);
        float fv = __shfl(v, qb+1, 64);
        float gv = __shfl(v, qb+2, 64);
        float ov = __shfl(v, qb+3, 64);
        if (leader) {
          float cnew = sigm(fv)*cstate[r4] + sigm(iv)*tanhf(gv);
          float hnew = sigm(ov)*tanhf(cnew);
          cstate[r4] = cnew;
          const int b = rg*16 + blocal;
          hseq[((long)b*L_ + t)*H_ + jglob] = hnew;
          cseq[((long)b*L_ + t)*H_ + jglob] = cnew;
          short hh, hl; splitbf(hnew, hh, hl);
          unsigned pk = (unsigned)(unsigned short)hh |
                        ((unsigned)(unsigned short)hl << 16);
          __hip_atomic_store(&hb[((long)(t&1)*B_ + b)*H_ + jglob], pk,
                             __ATOMIC_RELAXED, __HIP_MEMORY_SCOPE_AGENT);
        }
      }
      // per-rowgroup barrier (16 blocks), monotonic counter, no fences.
      // __syncthreads drains vmcnt(0) -> sc1 h-stores are at coherence point
      // before the arrive; sc1 poll loads read the coherence point directly.
      if (t < L_-1) {
        __syncthreads();
        if (tid == 0) {
          atomicAdd(cnt, 1);
          const int target = 16*(t+1);
          while (__hip_atomic_load(cnt, __ATOMIC_RELAXED,
                                   __HIP_MEMORY_SCOPE_AGENT) < target)
            __builtin_amdgcn_s_sleep(1);
        }
        __syncthreads();
      }
    }
  }
}

// ---------------------------------------------------------------------------
extern "C" void kernel_launch(void* const* d_in, const int* in_sizes, int n_in,
                              void* d_out, int out_size, void* d_ws, size_t ws_size,
                              hipStream_t stream)
{
  const float* x   = (const float*)d_in[0];
  const float* Wih = (const float*)d_in[1];
  const float* bih = (const float*)d_in[2];
  const float* Wmx = (const float*)d_in[3];
  const float* bmx = (const float*)d_in[4];
  const float* Wmh = (const float*)d_in[5];
  const float* bmh = (const float*)d_in[6];
  const float* Whm = (const float*)d_in[7];
  const float* bhm = (const float*)d_in[8];
  const float* Wa  = (const float*)d_in[9];
  const float* ba  = (const float*)d_in[10];

  float* out  = (float*)d_out;
  float* hseq = out;                           // (B, L, H)
  float* cseq = out + (size_t)B_*L_*H_;        // (B, L, H)
  float* xt   = out + (size_t)2*B_*L_*H_;      // (B, L, C)

  // ws carve (~24 MB)
  float*    G2ws   = (float*)d_ws;                      // 256*16384 f = 16 MB
  float*    beff_p = G2ws + (size_t)256*16384;          // 2048 f
  short*    W2h = (short*)(beff_p + N4H);               // 2048*512
  short*    W2l = W2h + (size_t)N4H*H_;
  short*    Wfh = W2l + (size_t)N4H*H_;                 // 2048*256
  short*    Wfl = Wfh + (size_t)N4H*C_;
  unsigned* hb  = (unsigned*)(Wfl + (size_t)N4H*C_);    // 2*256*512 u32
  int*      bar = (int*)(hb + (size_t)2*B_*H_);         // 512 ints

  xtilde_kernel<<<B_, 256, 0, stream>>>(x, Wa, ba, xt);
  beff_kernel<<<N4H/256, 256, 0, stream>>>(bih, bhm, bmx, bmh, Whm, beff_p);
  // W2 = Wmh@Whm  -> swizzled frag layout, kfrags=16 (K=512)
  gemm_fold<<<dim3(N4H/64, H_/64), 256, 0, stream>>>(
      Wmh, H_, Whm, nullptr, W2h, W2l, 16);
  // Weff = Wmx@Whm + Wih -> swizzled, kfrags=8 (K=256)
  gemm_fold<<<dim3(N4H/64, C_/64), 256, 0, stream>>>(
      Wmx, H_, Whm, Wih, Wfh, Wfl, 8);
  init_bar<<<1, 512, 0, stream>>>(bar);

  persist_kernel<<<256, 512, 0, stream>>>(
      x, Wfh, Wfl, W2h, W2l, beff_p, G2ws, hb, hseq, cseq, bar);
}